// Round 3
// baseline (109.148 us; speedup 1.0000x reference)
//
#include <hip/hip_runtime.h>
#include <hip/hip_bf16.h>

#define N_IMG 2048
#define K_TXT 128
#define D_IN  768
#define H_DIM 512
#define M_TOT (N_IMG + K_TXT)   // 2176 virtual rows (img ++ txt)
#define NK    (N_IMG * K_TXT)   // 262144 outputs
#define NTILE 16                // proj n-tiles (32 cols each)

typedef __bf16 bf16x8 __attribute__((ext_vector_type(8)));
typedef float  f32x4  __attribute__((ext_vector_type(4)));

// ---------------------------------------------------------------------------
// Kernel 1 (v3): P[r][h] = X[r] @ W1half (+ b1 for txt rows), bf16 MFMA.
// BK=128, wave-split-K: each of the 4 waves computes the FULL 32x32 tile
// over its private 32-wide k-slice (2x2 fragments -> 4 ds_read_b128 : 4 MFMA,
// ratio 1.0 vs old 2.0), 6 iterations -> 12 barriers (was 24).
// Epilogue: cross-wave k-reduction of the four 32x32 partials via LDS
// (aliased onto the staging buffers), then P-write + pw-row partials.
// Stride 136 bf16 = 68 dw/row: all write/read quarter-wave phases are
// 2-way max = free (m136).
// ---------------------------------------------------------------------------
__global__ __launch_bounds__(256) void proj_kernel(
    const float* __restrict__ img, const float* __restrict__ txt,
    const float* __restrict__ W1, const float* __restrict__ b1,
    const float* __restrict__ W2, float* __restrict__ P,
    float* __restrict__ pw2)
{
    __shared__ __align__(16) __bf16 smem[2][32][136];   // A | B staging, 17.4 KB
    __shared__ float lds_pw[32];
    float* red = reinterpret_cast<float*>(&smem[0][0][0]);  // 16 KB epilogue buf

    const int tid = threadIdx.x;
    const int n0 = (blockIdx.x & (NTILE - 1)) * 32;  // 16 n-tiles
    const int m0 = (blockIdx.x >> 4) * 32;           // 68 m-tiles
    const bool is_txt = (m0 >= N_IMG);
    const float* X  = is_txt ? (txt + (size_t)(m0 - N_IMG) * D_IN)
                             : (img + (size_t)m0 * D_IN);
    const float* Wb = W1 + (is_txt ? (size_t)D_IN * H_DIM : 0);

    const int wave = tid >> 6, lane = tid & 63;
    const int quad = lane >> 4, lm = lane & 15;
    const int ksub = wave * 32;                      // this wave's k-slice

    const int ar = tid >> 3, ak = (tid & 7) * 16;    // A: row ar, 16 floats at ak
    const int bn = tid & 31, bk = (tid >> 5) * 16;   // B: col bn, 16 k at bk

    f32x4 acc[2][2] = {};
    f32x4 aR[4];
    float bR[16];

    auto loadA = [&](int kc) {
        const float* ap = X + (size_t)ar * D_IN + kc + ak;
        #pragma unroll
        for (int j = 0; j < 4; ++j) aR[j] = *(const f32x4*)(ap + j * 4);
    };
    auto loadB = [&](int kc) {
        #pragma unroll
        for (int j = 0; j < 16; ++j)
            bR[j] = Wb[(size_t)(kc + bk + j) * H_DIM + n0 + bn];
    };

    union Pack16 { __bf16 h[16]; uint4 u[2]; };

    loadA(0); loadB(0);

    for (int it = 0; it < 6; ++it) {
        Pack16 pa;
        #pragma unroll
        for (int j = 0; j < 4; ++j)
            #pragma unroll
            for (int c = 0; c < 4; ++c) pa.h[j * 4 + c] = (__bf16)aR[j][c];
        *(uint4*)&smem[0][ar][ak]     = pa.u[0];
        *(uint4*)&smem[0][ar][ak + 8] = pa.u[1];
        Pack16 pb;
        #pragma unroll
        for (int j = 0; j < 16; ++j) pb.h[j] = (__bf16)bR[j];
        *(uint4*)&smem[1][bn][bk]     = pb.u[0];
        *(uint4*)&smem[1][bn][bk + 8] = pb.u[1];
        __syncthreads();

        if (it < 5) { loadA((it + 1) * 128); loadB((it + 1) * 128); }

        bf16x8 af0 = *(bf16x8*)&smem[0][lm][ksub + quad * 8];
        bf16x8 af1 = *(bf16x8*)&smem[0][16 + lm][ksub + quad * 8];
        bf16x8 bf0 = *(bf16x8*)&smem[1][lm][ksub + quad * 8];
        bf16x8 bf1 = *(bf16x8*)&smem[1][16 + lm][ksub + quad * 8];
        acc[0][0] = __builtin_amdgcn_mfma_f32_16x16x32_bf16(af0, bf0, acc[0][0], 0, 0, 0);
        acc[0][1] = __builtin_amdgcn_mfma_f32_16x16x32_bf16(af0, bf1, acc[0][1], 0, 0, 0);
        acc[1][0] = __builtin_amdgcn_mfma_f32_16x16x32_bf16(af1, bf0, acc[1][0], 0, 0, 0);
        acc[1][1] = __builtin_amdgcn_mfma_f32_16x16x32_bf16(af1, bf1, acc[1][1], 0, 0, 0);
        __syncthreads();
    }

    // cross-wave k-reduction: each wave dumps its 32x32 partial into red[]
    // C/D layout col=lane&15, row=quad*4+r [m89-verified]
    #pragma unroll
    for (int mf = 0; mf < 2; ++mf)
        #pragma unroll
        for (int nf = 0; nf < 2; ++nf)
            #pragma unroll
            for (int r = 0; r < 4; ++r)
                red[wave * 1024 + (mf * 16 + quad * 4 + r) * 32 + nf * 16 + lm]
                    = acc[mf][nf][r];
    __syncthreads();

    const int orow = tid >> 3;          // 0..31
    const int oc4  = (tid & 7) * 4;     // 0..28
    f32x4 v = {};
    #pragma unroll
    for (int w = 0; w < 4; ++w)
        v += *(f32x4*)&red[w * 1024 + orow * 32 + oc4];

    const int gm = m0 + orow;
    const int gn = n0 + oc4;
    if (is_txt) v += *(const f32x4*)(b1 + gn);
    *(f32x4*)&P[(size_t)gm * H_DIM + gn] = v;

    // pw-row partial: 0.5 * v . W2 over this thread's 4 cols, reduced over
    // the 8 threads (32 cols) of the row
    f32x4 w2 = *(const f32x4*)(W2 + gn);
    float rv = 0.5f * (v[0] * w2[0] + v[1] * w2[1] + v[2] * w2[2] + v[3] * w2[3]);
    #pragma unroll
    for (int m = 1; m < 8; m <<= 1) rv += __shfl_xor(rv, m, 64);
    if ((tid & 7) == 0) lds_pw[orow] = rv;
    __syncthreads();
    if (tid < 32)
        pw2[(size_t)(blockIdx.x & (NTILE - 1)) * M_TOT + m0 + tid] = lds_pw[tid];
}

// ---------------------------------------------------------------------------
// Kernel 2 (fused sim+reduce): out[n,k] = 0.5*sum_h |P_img[n,h]+P_txt[k,h]|*W2[h]
//                                         + pn[n] + pk[k] + b2
// Tile 32n x 32k x FULL 512h; grid 64x4 = 256 blocks (1/CU), 256 thr.
// Thread = 4n x 1k: per h4-iter 1 ds_read_b128 : 32 VALU -> VALU-bound
// (per-CU LDS 6.1K cyc < VALU 8.2K cyc). Eliminates the P2 round-trip and
// the third kernel launch. Bs XOR-swizzle c4^(row&7): the 16-lane same-col
// read across rows is 2-way = free (verified: banks g=(4(row&1)+((c4^row)&7))
// mod 8 are a bijection over 8 groups per 8 rows).
// pn/pk: 16-slice pw2 sums done once per block into LDS.
// ---------------------------------------------------------------------------
__global__ __launch_bounds__(256) void sim_kernel(
    const float* __restrict__ P, const float* __restrict__ W2,
    const float* __restrict__ pw2, const float* __restrict__ b2,
    float* __restrict__ out)
{
    __shared__ __align__(16) float Bs[32][H_DIM];   // 64 KB txt slab, swizzled
    __shared__ float pn_l[32], pk_l[32];

    const int tid = threadIdx.x;
    const int n0 = blockIdx.x * 32;
    const int k0 = blockIdx.y * 32;

    // stage txt rows [k0, k0+32) x full h: 4096 f32x4 chunks, 16 per thread
    #pragma unroll
    for (int i = 0; i < 16; ++i) {
        const int flat = tid + i * 256;
        const int row = flat >> 7, c4 = flat & 127;
        f32x4 v = *(const f32x4*)(P + (size_t)(N_IMG + k0 + row) * H_DIM + c4 * 4);
        *(f32x4*)&Bs[row][(c4 ^ (row & 7)) * 4] = v;
    }
    if (tid < 32) {
        float s = 0.f;
        #pragma unroll
        for (int sl = 0; sl < NTILE; ++sl)
            s += pw2[(size_t)sl * M_TOT + n0 + tid];
        pn_l[tid] = s;
    } else if (tid < 64) {
        const int k = tid - 32;
        float s = 0.f;
        #pragma unroll
        for (int sl = 0; sl < NTILE; ++sl)
            s += pw2[(size_t)sl * M_TOT + N_IMG + k0 + k];
        pk_l[k] = s;
    }
    __syncthreads();

    const int tx = tid & 31;        // k row
    const int ty = tid >> 5;        // n quad: rows n0 + ty*4 .. +3
    const int sx = tx & 7;
    const float* pA = P + (size_t)(n0 + ty * 4) * H_DIM;

    f32x4 acc[4] = {};
    #pragma unroll 8
    for (int h4 = 0; h4 < H_DIM / 4; ++h4) {
        f32x4 w = *(const f32x4*)(W2 + h4 * 4);            // wave-uniform
        f32x4 b = *(f32x4*)&Bs[tx][(h4 ^ sx) * 4];
        #pragma unroll
        for (int nn = 0; nn < 4; ++nn) {
            f32x4 a = *(const f32x4*)(pA + (size_t)nn * H_DIM + h4 * 4);  // L1 bcast
            #pragma unroll
            for (int hh = 0; hh < 4; ++hh)
                acc[nn][hh] = fmaf(fabsf(a[hh] + b[hh]), w[hh], acc[nn][hh]);
        }
    }

    const float addc = pk_l[tx] + b2[0];
    #pragma unroll
    for (int nn = 0; nn < 4; ++nn) {
        const float s = (acc[nn][0] + acc[nn][1]) + (acc[nn][2] + acc[nn][3]);
        out[(size_t)(n0 + ty * 4 + nn) * K_TXT + k0 + tx]
            = 0.5f * s + pn_l[ty * 4 + nn] + addc;
    }
}

// ---------------------------------------------------------------------------
extern "C" void kernel_launch(void* const* d_in, const int* in_sizes, int n_in,
                              void* d_out, int out_size, void* d_ws, size_t ws_size,
                              hipStream_t stream) {
    const float* img = (const float*)d_in[0];
    const float* txt = (const float*)d_in[1];
    const float* W1  = (const float*)d_in[2];
    const float* b1  = (const float*)d_in[3];
    const float* W2  = (const float*)d_in[4];
    const float* b2  = (const float*)d_in[5];
    float* out = (float*)d_out;

    float* P   = (float*)d_ws;                  // 2176 x 512 fp32 = 4.46 MB
    float* pw2 = P + (size_t)M_TOT * H_DIM;     // 16 x 2176 fp32 slices

    proj_kernel<<<dim3(68 * NTILE),              256, 0, stream>>>(img, txt, W1, b1, W2, P, pw2);
    sim_kernel <<<dim3(N_IMG / 32, K_TXT / 32),  256, 0, stream>>>(P, W2, pw2, b2, out);
}

// Round 4
// 100.997 us; speedup vs baseline: 1.0807x; 1.0807x over previous
//
#include <hip/hip_runtime.h>
#include <hip/hip_bf16.h>

#define N_IMG 2048
#define K_TXT 128
#define D_IN  768
#define H_DIM 512
#define M_TOT (N_IMG + K_TXT)   // 2176 virtual rows (img ++ txt)
#define NK    (N_IMG * K_TXT)   // 262144 outputs
#define NTILE 16                // proj n-tiles (32 cols each)

typedef __bf16 bf16x8 __attribute__((ext_vector_type(8)));
typedef float  f32x4  __attribute__((ext_vector_type(4)));

// ---------------------------------------------------------------------------
// Kernel 1: P[r][h] = X[r] @ W1half (+ b1 for txt rows), bf16 MFMA, fp32 out.
// 1088 tiles of 32m x 32n (4.25 blocks/CU), BK=64, register prefetch.
// LDS stride 72 bf16 = 36 dwords/row: every ds_write_b128/ds_read_b128 phase
// is 2-way max = free (m136). Epilogue reduces pw-row partials across the
// block's 4 waves in LDS and writes deterministic slices pw2[ntile][row]
// (no atomics, no memset prerequisite).
// [best-verified config: 100.14 µs]
// ---------------------------------------------------------------------------
__global__ __launch_bounds__(256) void proj_kernel(
    const float* __restrict__ img, const float* __restrict__ txt,
    const float* __restrict__ W1, const float* __restrict__ b1,
    const float* __restrict__ W2, float* __restrict__ P,
    float* __restrict__ pw2)
{
    __shared__ __align__(16) __bf16 As[32][72];
    __shared__ __align__(16) __bf16 Bs[32][72];
    __shared__ float lds_pw[32];

    const int tid = threadIdx.x;
    const int n0 = (blockIdx.x & (NTILE - 1)) * 32;  // 16 n-tiles
    const int m0 = (blockIdx.x >> 4) * 32;           // 68 m-tiles
    const bool is_txt = (m0 >= N_IMG);
    const float* X  = is_txt ? (txt + (size_t)(m0 - N_IMG) * D_IN)
                             : (img + (size_t)m0 * D_IN);
    const float* Wb = W1 + (is_txt ? (size_t)D_IN * H_DIM : 0);

    const int wave = tid >> 6, lane = tid & 63;
    const int wm = (wave >> 1) * 16, wn = (wave & 1) * 16;
    const int quad = lane >> 4, lm = lane & 15;

    const int ar = tid >> 3, ak = (tid & 7) * 8;   // A: row ar, 8 floats at ak
    const int bn = tid & 31, bk = (tid >> 5) * 8;  // B: col bn, 8 k at bk

    f32x4 acc = {0.f, 0.f, 0.f, 0.f};
    f32x4 aR0, aR1;
    float bR[8];

    auto loadA = [&](int kc) {
        const float* ap = X + (size_t)ar * D_IN + kc + ak;
        aR0 = *(const f32x4*)(ap + 0);
        aR1 = *(const f32x4*)(ap + 4);
    };
    auto loadB = [&](int kc) {
        #pragma unroll
        for (int j = 0; j < 8; ++j)
            bR[j] = Wb[(size_t)(kc + bk + j) * H_DIM + n0 + bn];
    };

    union BPack { __bf16 h[8]; uint4 u; };

    loadA(0); loadB(0);

    for (int it = 0; it < 12; ++it) {
        BPack pa;
        #pragma unroll
        for (int j = 0; j < 4; ++j) { pa.h[j] = (__bf16)aR0[j]; pa.h[4+j] = (__bf16)aR1[j]; }
        *(uint4*)&As[ar][ak] = pa.u;
        BPack q;
        #pragma unroll
        for (int j = 0; j < 8; ++j) q.h[j] = (__bf16)bR[j];
        *(uint4*)&Bs[bn][bk] = q.u;
        __syncthreads();

        if (it < 11) { loadA((it + 1) * 64); loadB((it + 1) * 64); }

        #pragma unroll
        for (int sub = 0; sub < 2; ++sub) {
            bf16x8 af = *(bf16x8*)&As[wm + lm][sub * 32 + quad * 8];
            bf16x8 bf = *(bf16x8*)&Bs[wn + lm][sub * 32 + quad * 8];
            acc = __builtin_amdgcn_mfma_f32_16x16x32_bf16(af, bf, acc, 0, 0, 0);
        }
        __syncthreads();
    }

    // epilogue: C/D layout col=lane&15, row=quad*4+r [m89-verified];
    // write P and accumulate pw-row partials (0.5 * P . W2 over tile cols)
    float rv[4];
    {
        const int gn = n0 + wn + lm;
        const float badd = is_txt ? b1[gn] : 0.0f;
        const float w2h = 0.5f * W2[gn];
        #pragma unroll
        for (int r = 0; r < 4; ++r) {
            const int gm = m0 + wm + quad * 4 + r;
            const float v = acc[r] + badd;
            P[(size_t)gm * H_DIM + gn] = v;
            rv[r] = v * w2h;
        }
    }
    #pragma unroll
    for (int m = 1; m < 16; m <<= 1) {
        #pragma unroll
        for (int r = 0; r < 4; ++r) rv[r] += __shfl_xor(rv[r], m, 64);
    }
    // combine the 2 wn-halves per row across waves via LDS
    if (tid < 32) lds_pw[tid] = 0.f;
    __syncthreads();
    if (lm == 0) {
        #pragma unroll
        for (int r = 0; r < 4; ++r)
            atomicAdd(&lds_pw[wm + quad * 4 + r], rv[r]);
    }
    __syncthreads();
    if (tid < 32)
        pw2[(size_t)(blockIdx.x & (NTILE - 1)) * M_TOT + m0 + tid] = lds_pw[tid];
}

// ---------------------------------------------------------------------------
// Kernel 2: P2[hs][n][k] = sum_{h in slab hs} |P_img[n,h] + P_txt[k,h]| * 0.5*W2[h]
// Tile 32n x 64k x 64h; grid 64x2x8 = 1024 blocks (4/CU = 16 waves/CU).
// Bs[64][67]: 4-row lane stride = 268 dwords = 12 mod 32 -> conflict-free.
// ---------------------------------------------------------------------------
__global__ __launch_bounds__(256) void sim_kernel(
    const float* __restrict__ P, const float* __restrict__ W2,
    float* __restrict__ P2)
{
    __shared__ __align__(16) float Bs[64][67];
    __shared__ __align__(16) float Ws[64];

    const int tid = threadIdx.x;
    const int n0 = blockIdx.x * 32;
    const int k0 = blockIdx.y * 64;
    const int hs = blockIdx.z;
    const int hc = hs * 64;

    #pragma unroll
    for (int i = 0; i < 4; ++i) {
        const int flat = tid + i * 256;
        const int row = flat >> 4, c4 = flat & 15;
        f32x4 v = *(const f32x4*)(P + (size_t)(N_IMG + k0 + row) * H_DIM + hc + c4 * 4);
        *(f32x4*)&Bs[row][c4 * 4] = v;
    }
    if (tid < 16) {
        f32x4 w = *(const f32x4*)(W2 + hc + tid * 4);
        w *= 0.5f;
        *(f32x4*)&Ws[tid * 4] = w;
    }
    __syncthreads();

    const int tx = tid & 15;   // k: 4 consecutive
    const int ty = tid >> 4;   // n: 2 consecutive rows
    const float* pA = P + (size_t)(n0 + ty * 2) * H_DIM + hc;

    f32x4 acc0 = {0.f, 0.f, 0.f, 0.f};
    f32x4 acc1 = {0.f, 0.f, 0.f, 0.f};

    #pragma unroll 4
    for (int h4 = 0; h4 < 16; ++h4) {
        f32x4 a0 = *(const f32x4*)(pA + h4 * 4);
        f32x4 a1 = *(const f32x4*)(pA + H_DIM + h4 * 4);
        f32x4 w  = *(f32x4*)&Ws[h4 * 4];
        f32x4 b[4];
        #pragma unroll
        for (int j = 0; j < 4; ++j) b[j] = *(f32x4*)&Bs[tx * 4 + j][h4 * 4];

        #pragma unroll
        for (int j = 0; j < 4; ++j) {
            #pragma unroll
            for (int hh = 0; hh < 4; ++hh) {
                const float t0 = a0[hh] + b[j][hh];
                acc0[j] = fmaf(fabsf(t0), w[hh], acc0[j]);
                const float t1 = a1[hh] + b[j][hh];
                acc1[j] = fmaf(fabsf(t1), w[hh], acc1[j]);
            }
        }
    }

    float* o = P2 + (size_t)hs * NK + (size_t)(n0 + ty * 2) * K_TXT + k0 + tx * 4;
    *(f32x4*)o = acc0;
    *(f32x4*)(o + K_TXT) = acc1;
}

// ---------------------------------------------------------------------------
// Kernel 3: out[n,k] = pw[n] + pw[N+k] + b2 + sum_{hs<8} P2[hs][n][k]
// where pw[r] = sum_{s<16} pw2[s][r]  (L2-resident slice reads)
// ---------------------------------------------------------------------------
__global__ __launch_bounds__(256) void reduce_kernel(
    const float* __restrict__ P2, const float* __restrict__ pw2,
    const float* __restrict__ b2, float* __restrict__ out)
{
    const int idx = blockIdx.x * 256 + threadIdx.x;   // f32x4 index, 65536 total
    const int n  = idx >> 5;
    const int k4 = (idx & 31) * 4;
    const size_t base = (size_t)n * K_TXT + k4;

    f32x4 s = {0.f, 0.f, 0.f, 0.f};
    #pragma unroll
    for (int hs = 0; hs < 8; ++hs)
        s += *(const f32x4*)(P2 + (size_t)hs * NK + base);

    float pn = 0.f;
    f32x4 pk = {0.f, 0.f, 0.f, 0.f};
    #pragma unroll
    for (int sl = 0; sl < NTILE; ++sl) {
        const float* pws = pw2 + (size_t)sl * M_TOT;
        pn += pws[n];
        pk += *(const f32x4*)(pws + N_IMG + k4);
    }

    const float add = pn + b2[0];
    s[0] += add + pk[0]; s[1] += add + pk[1];
    s[2] += add + pk[2]; s[3] += add + pk[3];
    *(f32x4*)(out + base) = s;
}

// ---------------------------------------------------------------------------
extern "C" void kernel_launch(void* const* d_in, const int* in_sizes, int n_in,
                              void* d_out, int out_size, void* d_ws, size_t ws_size,
                              hipStream_t stream) {
    const float* img = (const float*)d_in[0];
    const float* txt = (const float*)d_in[1];
    const float* W1  = (const float*)d_in[2];
    const float* b1  = (const float*)d_in[3];
    const float* W2  = (const float*)d_in[4];
    const float* b2  = (const float*)d_in[5];
    float* out = (float*)d_out;

    float* P   = (float*)d_ws;                  // 2176 x 512 fp32 = 4.46 MB
    float* pw2 = P + (size_t)M_TOT * H_DIM;     // 16 x 2176 fp32 (deterministic slices)
    float* P2  = pw2 + (size_t)NTILE * M_TOT;   // 8 x 2048 x 128 fp32 = 8.4 MB

    proj_kernel  <<<dim3(68 * NTILE),           256, 0, stream>>>(img, txt, W1, b1, W2, P, pw2);
    sim_kernel   <<<dim3(N_IMG / 32, K_TXT / 64, H_DIM / 64), 256, 0, stream>>>(P, W2, P2);
    reduce_kernel<<<dim3(NK / 4 / 256),         256, 0, stream>>>(P2, pw2, b2, out);
}